// Round 10
// baseline (22764.447 us; speedup 1.0000x reference)
//
#include <hip/hip_runtime.h>
#include <hip/hip_cooperative_groups.h>

#define B_ 64
#define H_ 1024
#define IN_ 512
#define S_ 256
#define L_ 6
#define NG_ 4096
#define NTASK 768            // 6 cells * 128 col-slices (8 H-cols x 4 gates)
#define NTICK (S_ + L_ - 1)

typedef __bf16 bf16x8 __attribute__((ext_vector_type(8)));
typedef float f32x4 __attribute__((ext_vector_type(4)));
typedef unsigned short ushort8v __attribute__((ext_vector_type(8)));
typedef unsigned short ushort_t;

#define WP_BYTES 96468992ul
#define XB_BYTES 16777216ul
#define HBF_ELEMS 786432ul          // 2 slots * L * 65536
#define LSLOT 65536ul               // packed h per layer (64 rows x 1024 K)
#define XSLOT 32768ul               // packed x per timestep (64 x 512)

// panel per (l,jb): chunk-major units (c*4 + nf*2 + ks) of 512 ushorts
__host__ __device__ __forceinline__ size_t poff(int l, int jb) {
  return (l == 0) ? (size_t)jb * 49152ul
                  : 6291456ul + ((size_t)(l - 1) * 128 + jb) * 65536ul;
}

#define MFMA16(a, b, c) __builtin_amdgcn_mfma_f32_16x16x32_bf16(a, b, c, 0, 0, 0)
#define WAITN(n) asm volatile("s_waitcnt vmcnt(" #n ")" ::: "memory")
#define SB0() __builtin_amdgcn_sched_barrier(0)

__device__ __forceinline__ unsigned short f2bf(float f) {
  union { float f; unsigned u; } v; v.f = f;
  unsigned r = v.u + 0x7fffu + ((v.u >> 16) & 1u);
  return (unsigned short)(r >> 16);
}

// ---- one-time weight pack: unit (c, nf, ks), lane, e:
// W[k][n], k = c*64 + ks*32 + (lane>>4)*8 + e,
// n = (nf*2 + ((lane&15)>>3))*1024 + jb*8 + (lane&7); V part at k >= KU.
__global__ void k_pack_w(const float* __restrict__ U0, const float* __restrict__ V0,
                         const float* __restrict__ U, const float* __restrict__ V,
                         ushort_t* __restrict__ Wp) {
  const int bx = blockIdx.x;              // 0..767
  const int l = bx >> 7, jb = bx & 127;
  ushort_t* __restrict__ panel = Wp + poff(l, jb);
  const int KU = (l == 0) ? IN_ : H_;
  const int NU = KU >> 6;
  const int NCH = NU + 16;
  const float* __restrict__ Usrc = (l == 0) ? U0 : U + (size_t)(l - 1) * H_ * NG_;
  const float* __restrict__ Vsrc = (l == 0) ? V0 : V + (size_t)(l - 1) * H_ * NG_;
  const int t = threadIdx.x, lane = t & 63, g4 = t >> 6;
  const int l15 = lane & 15, kg = lane >> 4;
  for (int p = 0; p < NCH; ++p) {
    const int gi = p * 4 + g4;
    const int c = gi >> 2, u = gi & 3, nf = u >> 1, ks = u & 1;
    const int n = (nf * 2 + (l15 >> 3)) * 1024 + jb * 8 + (l15 & 7);
    const int k = c * 64 + ks * 32 + kg * 8;
    const float* __restrict__ src =
        (c < NU) ? (Usrc + (size_t)k * NG_ + n)
                 : (Vsrc + (size_t)(k - KU) * NG_ + n);
    ushort8v uv;
#pragma unroll
    for (int e = 0; e < 8; ++e) uv[e] = f2bf(src[(size_t)e * NG_]);
    *(ushort8v*)(panel + (size_t)gi * 512 + lane * 8) = uv;
  }
}

// ---- one-time x -> bf16 in packed-A unit order, per timestep ----
__global__ void k_cvt_x(const float* __restrict__ x, ushort_t* __restrict__ xb) {
  const int tt = blockIdx.x;
  const int tid = threadIdx.x;
  const int b = tid >> 2, kq = (tid & 3) << 7;
  const float* __restrict__ src = x + ((size_t)b * S_ + tt) * IN_ + kq;
  ushort_t* __restrict__ dst = xb + (size_t)tt * XSLOT;
  const int w = b >> 4, l15 = b & 15;
#pragma unroll
  for (int kk = 0; kk < 128; kk += 8) {
    float4 v0 = *(const float4*)(src + kk);
    float4 v1 = *(const float4*)(src + kk + 4);
    ushort8v u = { f2bf(v0.x), f2bf(v0.y), f2bf(v0.z), f2bf(v0.w),
                   f2bf(v1.x), f2bf(v1.y), f2bf(v1.z), f2bf(v1.w) };
    const int k = kq + kk;
    const int ks = k >> 5, kg = (k & 31) >> 3;
    *(ushort8v*)(dst + (((size_t)ks * 4 + w) * 64 + kg * 16 + l15) * 8) = u;
  }
}

// Per-wave GEMM over K: 16 rows x 32 N-cols, all operands VGPR-direct.
// Depth-3 register pipeline; sched_barrier(0) pins loads AND MFMAs (rule #18).
template<int NCH>
__device__ __forceinline__ void gemm_tick(f32x4 acc[2],
                                          const ushort_t* __restrict__ panel,
                                          const ushort_t* __restrict__ A1,
                                          const ushort_t* __restrict__ A2,
                                          int w, int lane) {
  constexpr int NU = NCH - 16;
  bf16x8 Wb[3][4];
  bf16x8 Ab[3][2];
#define LDU(p) (*(const bf16x8*)(p))
#define ISSUE(c) do { \
    const ushort_t* wp_ = panel + (size_t)(c) * 2048 + lane * 8; \
    Wb[(c) % 3][0] = LDU(wp_); \
    Wb[(c) % 3][1] = LDU(wp_ + 512); \
    Wb[(c) % 3][2] = LDU(wp_ + 1024); \
    Wb[(c) % 3][3] = LDU(wp_ + 1536); \
    const ushort_t* ap_ = ((c) < NU \
        ? A1 + ((size_t)(2 * (c)) * 4 + w) * 512 \
        : A2 + ((size_t)(2 * ((c) - NU)) * 4 + w) * 512) + lane * 8; \
    Ab[(c) % 3][0] = LDU(ap_); \
    Ab[(c) % 3][1] = LDU(ap_ + 2048); \
  } while (0)
  ISSUE(0); ISSUE(1); ISSUE(2);
  SB0();
#pragma unroll
  for (int c = 0; c < NCH; ++c) {
    const int rem = NCH - 1 - c;
    if (rem >= 2) { WAITN(12); }
    else if (rem == 1) { WAITN(6); }
    else { WAITN(0); }
    SB0();                              // pin: nothing crosses the wait
    acc[0] = MFMA16(Ab[c % 3][0], Wb[c % 3][0], acc[0]);  // ks0 nf0
    acc[1] = MFMA16(Ab[c % 3][0], Wb[c % 3][2], acc[1]);  // ks0 nf1
    acc[0] = MFMA16(Ab[c % 3][1], Wb[c % 3][1], acc[0]);  // ks1 nf0
    acc[1] = MFMA16(Ab[c % 3][1], Wb[c % 3][3], acc[1]);  // ks1 nf1
    SB0();                              // MFMAs stay here
    if (c + 3 < NCH) ISSUE(c + 3);      // refill bank just consumed
    SB0();                              // loads stay here
  }
#undef ISSUE
#undef LDU
}

__global__ void __launch_bounds__(256, 4)
k_lstm(const ushort_t* __restrict__ xb,
       const ushort_t* __restrict__ Wp,
       const float* __restrict__ b0,
       const float* __restrict__ bL,
       ushort_t* __restrict__ hbf,   // [2][L][LSLOT] packed bf16, pre-zeroed
       float* __restrict__ out, int multi) {
  cooperative_groups::grid_group grid = cooperative_groups::this_grid();
  float* __restrict__ seq = out;                           // [B][S][H]
  float* __restrict__ hf = out + (size_t)B_ * S_ * H_;     // [L][B][H]
  float* __restrict__ cf = hf + (size_t)L_ * B_ * H_;      // [L][B][H]
  __shared__ float hstF[512];   // 4 waves x 16 rows x 8 cols

  const int tid = threadIdx.x;
  const int w = tid >> 6;        // wave: rows w*16..w*16+15
  const int lane = tid & 63;
  const int l15 = lane & 15;
  const int kg = lane >> 4;
  const bool lo = (l15 < 8);
  const int wg = blockIdx.x;
  const int nwg = gridDim.x;

  // XCD-clustered task map when fully resident (round-robin dispatch: wg%8=XCD)
  const int task0 = (nwg == NTASK) ? ((wg & 7) * 96 + (wg >> 3)) : wg;

  float creg[4] = {0.f, 0.f, 0.f, 0.f};

  for (int T = 0; T < NTICK; ++T) {
    for (int task = task0; task < NTASK; task += nwg) {
      const int l = task >> 7;
      const int jb = task & 127;
      const int t = T - l;
      if (t < 0 || t >= S_) continue;
      const ushort_t* __restrict__ hprev = hbf + (size_t)((T + 1) & 1) * (L_ * LSLOT);
      ushort_t* __restrict__ hcur = hbf + (size_t)(T & 1) * (L_ * LSLOT);
      const ushort_t* __restrict__ panel = Wp + poff(l, jb);
      const ushort_t* __restrict__ A2 = hprev + (size_t)l * LSLOT;

      f32x4 acc[2];
      acc[0] = (f32x4){0.f, 0.f, 0.f, 0.f};
      acc[1] = (f32x4){0.f, 0.f, 0.f, 0.f};
      if (l == 0)
        gemm_tick<24>(acc, panel, xb + (size_t)t * XSLOT, A2, w, lane);
      else
        gemm_tick<32>(acc, panel, hprev + (size_t)(l - 1) * LSLOT, A2, w, lane);

      const int hc = (jb << 3) + (l15 & 7);
      const float* __restrict__ bias = (l == 0) ? b0 : (bL + (size_t)(l - 1) * NG_);
      const float bi = bias[hc];
      const float bfv = bias[1024 + hc];
      const float bgv = bias[2048 + hc];
      const float bov = bias[3072 + hc];

#pragma unroll
      for (int j = 0; j < 4; ++j) {
        float a0 = acc[0][j], a1 = acc[1][j];
        float p0 = __shfl_xor(a0, 8, 64);
        float p1 = __shfl_xor(a1, 8, 64);
        float zi = (lo ? a0 : p0) + bi;
        float zf = (lo ? p0 : a0) + bfv;
        float zg = (lo ? a1 : p1) + bgv;
        float zo = (lo ? p1 : a1) + bov;
        float iv = 1.f / (1.f + expf(-zi));
        float fv = 1.f / (1.f + expf(-zf));
        float gv = tanhf(zg);
        float ov = 1.f / (1.f + expf(-zo));
        const int r = w * 16 + kg * 4 + j;
        float cold;
        if (multi)
          cold = (t > 0) ? cf[((size_t)l * B_ + r) * H_ + hc] : 0.f;
        else
          cold = creg[j];
        float cn = fv * cold + iv * gv;
        creg[j] = cn;
        float hv = ov * tanhf(cn);
        if (lo) {
          hstF[w * 128 + (kg * 4 + j) * 8 + l15] = hv;
          if (multi || t == S_ - 1) cf[((size_t)l * B_ + r) * H_ + hc] = cn;
          if (t == S_ - 1) hf[((size_t)l * B_ + r) * H_ + hc] = hv;
        }
      }
      __syncthreads();
      if (kg == 0) {
        const int lr = l15;            // local row 0..15
        float4 v0 = *(const float4*)&hstF[w * 128 + lr * 8];
        float4 v1 = *(const float4*)&hstF[w * 128 + lr * 8 + 4];
        ushort8v u8 = { f2bf(v0.x), f2bf(v0.y), f2bf(v0.z), f2bf(v0.w),
                        f2bf(v1.x), f2bf(v1.y), f2bf(v1.z), f2bf(v1.w) };
        *(ushort8v*)(hcur + (size_t)l * LSLOT +
                     (((size_t)(jb >> 2) * 4 + w) * 64 + (jb & 3) * 16 + lr) * 8) = u8;
        if (l == L_ - 1) {
          float* sp = seq + (((size_t)(w * 16 + lr)) * S_ + t) * H_ + (jb << 3);
          *(float4*)sp = v0;
          *(float4*)(sp + 4) = v1;
        }
      }
      __syncthreads();                 // hstF safe before reuse
    }
    grid.sync();
  }
}

extern "C" void kernel_launch(void* const* d_in, const int* in_sizes, int n_in,
                              void* d_out, int out_size, void* d_ws, size_t ws_size,
                              hipStream_t stream) {
  const float* x = (const float*)d_in[0];
  const float* U0 = (const float*)d_in[1];
  const float* V0 = (const float*)d_in[2];
  const float* b0 = (const float*)d_in[3];
  const float* U = (const float*)d_in[4];
  const float* V = (const float*)d_in[5];
  const float* bL = (const float*)d_in[6];
  float* out = (float*)d_out;

  char* ws = (char*)d_ws;
  unsigned short* Wp = (unsigned short*)ws;
  unsigned short* xb = (unsigned short*)(ws + WP_BYTES);
  unsigned short* hbf = (unsigned short*)(ws + WP_BYTES + XB_BYTES);

  hipLaunchKernelGGL(k_pack_w, dim3(NTASK), dim3(256), 0, stream, U0, V0, U, V, Wp);
  hipLaunchKernelGGL(k_cvt_x, dim3(S_), dim3(256), 0, stream, x, xb);
  hipMemsetAsync(hbf, 0, HBF_ELEMS * 2, stream);

  int maxB = 0;
  hipOccupancyMaxActiveBlocksPerMultiprocessor(&maxB, k_lstm, 256, 0);
  int nwg = maxB * 256;
  if (nwg > NTASK) nwg = NTASK;
  if (nwg < 64) nwg = 64;
  int multi = (nwg < NTASK) ? 1 : 0;

  void* args[] = { (void*)&xb, (void*)&Wp, (void*)&b0, (void*)&bL,
                   (void*)&hbf, (void*)&out, (void*)&multi };
  hipError_t e = hipLaunchCooperativeKernel((void*)k_lstm, dim3(nwg), dim3(256),
                                            args, 0, stream);
  if (e != hipSuccess) {
    (void)hipGetLastError();
    nwg = 256; multi = 1;
    void* args2[] = { (void*)&xb, (void*)&Wp, (void*)&b0, (void*)&bL,
                      (void*)&hbf, (void*)&out, (void*)&multi };
    hipLaunchCooperativeKernel((void*)k_lstm, dim3(nwg), dim3(256),
                               args2, 0, stream);
  }
}

// Round 11
// 15172.285 us; speedup vs baseline: 1.5004x; 1.5004x over previous
//
#include <hip/hip_runtime.h>
#include <hip/hip_cooperative_groups.h>

#define B_ 64
#define H_ 1024
#define IN_ 512
#define S_ 256
#define L_ 6
#define NG_ 4096
#define NTASK 768            // 6 cells * 128 col-slices (8 H-cols x 4 gates)
#define NTICK (S_ + L_ - 1)

typedef __bf16 bf16x8 __attribute__((ext_vector_type(8)));
typedef float f32x4 __attribute__((ext_vector_type(4)));
typedef unsigned short ushort8v __attribute__((ext_vector_type(8)));
typedef unsigned short ushort_t;

#define WP_BYTES 96468992ul
#define XB_BYTES 16777216ul
#define HBF_ELEMS 786432ul          // 2 slots * L * 65536
#define LSLOT 65536ul               // packed h per layer (64 rows x 1024 K)
#define XSLOT 32768ul               // packed x per timestep (64 x 512)

// panel per (l,jb): chunk-major units (c*4 + nf*2 + ks) of 512 ushorts
__host__ __device__ __forceinline__ size_t poff(int l, int jb) {
  return (l == 0) ? (size_t)jb * 49152ul
                  : 6291456ul + ((size_t)(l - 1) * 128 + jb) * 65536ul;
}

#define MFMA16(a, b, c) __builtin_amdgcn_mfma_f32_16x16x32_bf16(a, b, c, 0, 0, 0)
#define WAITN(n) asm volatile("s_waitcnt vmcnt(" #n ")" ::: "memory")
#define SB0() __builtin_amdgcn_sched_barrier(0)

__device__ __forceinline__ unsigned short f2bf(float f) {
  union { float f; unsigned u; } v; v.f = f;
  unsigned r = v.u + 0x7fffu + ((v.u >> 16) & 1u);
  return (unsigned short)(r >> 16);
}

// ---- one-time weight pack: unit (c, nf, ks), lane, e:
// W[k][n], k = c*64 + ks*32 + (lane>>4)*8 + e,
// n = (nf*2 + ((lane&15)>>3))*1024 + jb*8 + (lane&7); V part at k >= KU.
__global__ void k_pack_w(const float* __restrict__ U0, const float* __restrict__ V0,
                         const float* __restrict__ U, const float* __restrict__ V,
                         ushort_t* __restrict__ Wp) {
  const int bx = blockIdx.x;              // 0..767
  const int l = bx >> 7, jb = bx & 127;
  ushort_t* __restrict__ panel = Wp + poff(l, jb);
  const int KU = (l == 0) ? IN_ : H_;
  const int NU = KU >> 6;
  const int NCH = NU + 16;
  const float* __restrict__ Usrc = (l == 0) ? U0 : U + (size_t)(l - 1) * H_ * NG_;
  const float* __restrict__ Vsrc = (l == 0) ? V0 : V + (size_t)(l - 1) * H_ * NG_;
  const int t = threadIdx.x, lane = t & 63, g4 = t >> 6;
  const int l15 = lane & 15, kg = lane >> 4;
  for (int p = 0; p < NCH; ++p) {
    const int gi = p * 4 + g4;
    const int c = gi >> 2, u = gi & 3, nf = u >> 1, ks = u & 1;
    const int n = (nf * 2 + (l15 >> 3)) * 1024 + jb * 8 + (l15 & 7);
    const int k = c * 64 + ks * 32 + kg * 8;
    const float* __restrict__ src =
        (c < NU) ? (Usrc + (size_t)k * NG_ + n)
                 : (Vsrc + (size_t)(k - KU) * NG_ + n);
    ushort8v uv;
#pragma unroll
    for (int e = 0; e < 8; ++e) uv[e] = f2bf(src[(size_t)e * NG_]);
    *(ushort8v*)(panel + (size_t)gi * 512 + lane * 8) = uv;
  }
}

// ---- one-time x -> bf16 in packed-A unit order, per timestep ----
__global__ void k_cvt_x(const float* __restrict__ x, ushort_t* __restrict__ xb) {
  const int tt = blockIdx.x;
  const int tid = threadIdx.x;
  const int b = tid >> 2, kq = (tid & 3) << 7;
  const float* __restrict__ src = x + ((size_t)b * S_ + tt) * IN_ + kq;
  ushort_t* __restrict__ dst = xb + (size_t)tt * XSLOT;
  const int w = b >> 4, l15 = b & 15;
#pragma unroll
  for (int kk = 0; kk < 128; kk += 8) {
    float4 v0 = *(const float4*)(src + kk);
    float4 v1 = *(const float4*)(src + kk + 4);
    ushort8v u = { f2bf(v0.x), f2bf(v0.y), f2bf(v0.z), f2bf(v0.w),
                   f2bf(v1.x), f2bf(v1.y), f2bf(v1.z), f2bf(v1.w) };
    const int k = kq + kk;
    const int ks = k >> 5, kg = (k & 31) >> 3;
    *(ushort8v*)(dst + (((size_t)ks * 4 + w) * 64 + kg * 16 + l15) * 8) = u;
  }
}

// Per-wave GEMM over K: 16 rows x 32 N-cols, all operands VGPR-direct.
// Depth-3 register pipeline; sched_barrier(0) pins loads AND MFMAs (rule #18).
// launch_bounds(256,3) leaves ~170 VGPR so the banks allocate WITHOUT spill.
template<int NCH>
__device__ __forceinline__ void gemm_tick(f32x4 acc[2],
                                          const ushort_t* __restrict__ panel,
                                          const ushort_t* __restrict__ A1,
                                          const ushort_t* __restrict__ A2,
                                          int w, int lane) {
  constexpr int NU = NCH - 16;
  bf16x8 Wb[3][4];
  bf16x8 Ab[3][2];
#define LDU(p) (*(const bf16x8*)(p))
#define ISSUE(c) do { \
    const ushort_t* wp_ = panel + (size_t)(c) * 2048 + lane * 8; \
    Wb[(c) % 3][0] = LDU(wp_); \
    Wb[(c) % 3][1] = LDU(wp_ + 512); \
    Wb[(c) % 3][2] = LDU(wp_ + 1024); \
    Wb[(c) % 3][3] = LDU(wp_ + 1536); \
    const ushort_t* ap_ = ((c) < NU \
        ? A1 + ((size_t)(2 * (c)) * 4 + w) * 512 \
        : A2 + ((size_t)(2 * ((c) - NU)) * 4 + w) * 512) + lane * 8; \
    Ab[(c) % 3][0] = LDU(ap_); \
    Ab[(c) % 3][1] = LDU(ap_ + 2048); \
  } while (0)
  ISSUE(0); ISSUE(1); ISSUE(2);
  SB0();
#pragma unroll
  for (int c = 0; c < NCH; ++c) {
    const int rem = NCH - 1 - c;
    if (rem >= 2) { WAITN(12); }
    else if (rem == 1) { WAITN(6); }
    else { WAITN(0); }
    SB0();                              // pin: nothing crosses the wait
    acc[0] = MFMA16(Ab[c % 3][0], Wb[c % 3][0], acc[0]);  // ks0 nf0
    acc[1] = MFMA16(Ab[c % 3][0], Wb[c % 3][2], acc[1]);  // ks0 nf1
    acc[0] = MFMA16(Ab[c % 3][1], Wb[c % 3][1], acc[0]);  // ks1 nf0
    acc[1] = MFMA16(Ab[c % 3][1], Wb[c % 3][3], acc[1]);  // ks1 nf1
    SB0();                              // MFMAs stay here
    if (c + 3 < NCH) ISSUE(c + 3);      // refill bank just consumed
    SB0();                              // loads stay here
  }
#undef ISSUE
#undef LDU
}

__global__ void __launch_bounds__(256, 3)
k_lstm(const ushort_t* __restrict__ xb,
       const ushort_t* __restrict__ Wp,
       const float* __restrict__ b0,
       const float* __restrict__ bL,
       ushort_t* __restrict__ hbf,   // [2][L][LSLOT] packed bf16, pre-zeroed
       float* __restrict__ out, int multi) {
  cooperative_groups::grid_group grid = cooperative_groups::this_grid();
  float* __restrict__ seq = out;                           // [B][S][H]
  float* __restrict__ hf = out + (size_t)B_ * S_ * H_;     // [L][B][H]
  float* __restrict__ cf = hf + (size_t)L_ * B_ * H_;      // [L][B][H]
  __shared__ float hstF[512];   // 4 waves x 16 rows x 8 cols

  const int tid = threadIdx.x;
  const int w = tid >> 6;        // wave: rows w*16..w*16+15
  const int lane = tid & 63;
  const int l15 = lane & 15;
  const int kg = lane >> 4;
  const bool lo = (l15 < 8);
  const int wg = blockIdx.x;
  const int nwg = gridDim.x;

  float creg[4] = {0.f, 0.f, 0.f, 0.f};

  for (int T = 0; T < NTICK; ++T) {
    for (int task = wg; task < NTASK; task += nwg) {
      const int l = task >> 7;
      const int jb = task & 127;
      const int t = T - l;
      if (t < 0 || t >= S_) continue;
      const ushort_t* __restrict__ hprev = hbf + (size_t)((T + 1) & 1) * (L_ * LSLOT);
      ushort_t* __restrict__ hcur = hbf + (size_t)(T & 1) * (L_ * LSLOT);
      const ushort_t* __restrict__ panel = Wp + poff(l, jb);
      const ushort_t* __restrict__ A2 = hprev + (size_t)l * LSLOT;

      f32x4 acc[2];
      acc[0] = (f32x4){0.f, 0.f, 0.f, 0.f};
      acc[1] = (f32x4){0.f, 0.f, 0.f, 0.f};
      if (l == 0)
        gemm_tick<24>(acc, panel, xb + (size_t)t * XSLOT, A2, w, lane);
      else
        gemm_tick<32>(acc, panel, hprev + (size_t)(l - 1) * LSLOT, A2, w, lane);

      const int hc = (jb << 3) + (l15 & 7);
      const float* __restrict__ bias = (l == 0) ? b0 : (bL + (size_t)(l - 1) * NG_);
      const float bi = bias[hc];
      const float bfv = bias[1024 + hc];
      const float bgv = bias[2048 + hc];
      const float bov = bias[3072 + hc];

#pragma unroll
      for (int j = 0; j < 4; ++j) {
        float a0 = acc[0][j], a1 = acc[1][j];
        float p0 = __shfl_xor(a0, 8, 64);
        float p1 = __shfl_xor(a1, 8, 64);
        float zi = (lo ? a0 : p0) + bi;
        float zf = (lo ? p0 : a0) + bfv;
        float zg = (lo ? a1 : p1) + bgv;
        float zo = (lo ? p1 : a1) + bov;
        float iv = 1.f / (1.f + expf(-zi));
        float fv = 1.f / (1.f + expf(-zf));
        float gv = tanhf(zg);
        float ov = 1.f / (1.f + expf(-zo));
        const int r = w * 16 + kg * 4 + j;
        float cold;
        if (multi)
          cold = (t > 0) ? cf[((size_t)l * B_ + r) * H_ + hc] : 0.f;
        else
          cold = creg[j];
        float cn = fv * cold + iv * gv;
        creg[j] = cn;
        float hv = ov * tanhf(cn);
        if (lo) {
          hstF[w * 128 + (kg * 4 + j) * 8 + l15] = hv;
          if (multi || t == S_ - 1) cf[((size_t)l * B_ + r) * H_ + hc] = cn;
          if (t == S_ - 1) hf[((size_t)l * B_ + r) * H_ + hc] = hv;
        }
      }
      __syncthreads();
      if (kg == 0) {
        const int lr = l15;            // local row 0..15
        float4 v0 = *(const float4*)&hstF[w * 128 + lr * 8];
        float4 v1 = *(const float4*)&hstF[w * 128 + lr * 8 + 4];
        ushort8v u8 = { f2bf(v0.x), f2bf(v0.y), f2bf(v0.z), f2bf(v0.w),
                        f2bf(v1.x), f2bf(v1.y), f2bf(v1.z), f2bf(v1.w) };
        *(ushort8v*)(hcur + (size_t)l * LSLOT +
                     (((size_t)(jb >> 2) * 4 + w) * 64 + (jb & 3) * 16 + lr) * 8) = u8;
        if (l == L_ - 1) {
          float* sp = seq + (((size_t)(w * 16 + lr)) * S_ + t) * H_ + (jb << 3);
          *(float4*)sp = v0;
          *(float4*)(sp + 4) = v1;
        }
      }
      __syncthreads();                 // hstF safe before reuse
    }
    grid.sync();
  }
}

extern "C" void kernel_launch(void* const* d_in, const int* in_sizes, int n_in,
                              void* d_out, int out_size, void* d_ws, size_t ws_size,
                              hipStream_t stream) {
  const float* x = (const float*)d_in[0];
  const float* U0 = (const float*)d_in[1];
  const float* V0 = (const float*)d_in[2];
  const float* b0 = (const float*)d_in[3];
  const float* U = (const float*)d_in[4];
  const float* V = (const float*)d_in[5];
  const float* bL = (const float*)d_in[6];
  float* out = (float*)d_out;

  char* ws = (char*)d_ws;
  unsigned short* Wp = (unsigned short*)ws;
  unsigned short* xb = (unsigned short*)(ws + WP_BYTES);
  unsigned short* hbf = (unsigned short*)(ws + WP_BYTES + XB_BYTES);

  hipLaunchKernelGGL(k_pack_w, dim3(NTASK), dim3(256), 0, stream, U0, V0, U, V, Wp);
  hipLaunchKernelGGL(k_cvt_x, dim3(S_), dim3(256), 0, stream, x, xb);
  hipMemsetAsync(hbf, 0, HBF_ELEMS * 2, stream);

  int maxB = 0;
  hipOccupancyMaxActiveBlocksPerMultiprocessor(&maxB, k_lstm, 256, 0);
  int nwg = maxB * 256;
  if (nwg > NTASK) nwg = NTASK;
  if (nwg < 64) nwg = 64;
  int multi = (nwg < NTASK) ? 1 : 0;

  void* args[] = { (void*)&xb, (void*)&Wp, (void*)&b0, (void*)&bL,
                   (void*)&hbf, (void*)&out, (void*)&multi };
  hipError_t e = hipLaunchCooperativeKernel((void*)k_lstm, dim3(nwg), dim3(256),
                                            args, 0, stream);
  if (e != hipSuccess) {
    (void)hipGetLastError();
    nwg = 256; multi = 1;
    void* args2[] = { (void*)&xb, (void*)&Wp, (void*)&b0, (void*)&bL,
                      (void*)&hbf, (void*)&out, (void*)&multi };
    hipLaunchCooperativeKernel((void*)k_lstm, dim3(nwg), dim3(256),
                               args2, 0, stream);
  }
}